// Round 20
// baseline (320.046 us; speedup 1.0000x reference)
//
#include <hip/hip_runtime.h>
#include <hip/hip_bf16.h>
#include <math.h>

#define N_NODES 100000
#define N_EDGES 1600000
#define HC 64          // H*C
#define NHEADS 2
#define NLAYERS 4
#define ECLS 5
#define NBUCK 196              // ceil(N / 512); bucket = dst >> 9
#define NBLK 512               // coarse pass blocks
#define EPB (N_EDGES / NBLK)   // 3125 edges per coarse block (exact)
#define NGRP (N_NODES / 16)    // 6250 16-node groups (exact)
#define LIN0_BLOCKS 1024
#define FCAP 12288             // k_fine LDS staging capacity (avg bucket ~8163)
#define CHS 68                 // chbuf slot stride (floats)

typedef __attribute__((ext_vector_type(8))) short short8;
typedef __attribute__((ext_vector_type(4))) float floatx4;
typedef __attribute__((ext_vector_type(2))) float v2f;
union F8 { uint4 u; short8 s; };

// bf16 (stored as ushort) -> f32
__device__ inline float bf_lo(unsigned int u) { return __uint_as_float(u << 16); }
__device__ inline float bf_hi(unsigned int u) { return __uint_as_float(u & 0xffff0000u); }
// f32 -> bf16 bits, round-to-nearest-even
__device__ inline unsigned short f2bf(float f) {
    unsigned int u = __float_as_uint(f);
    u += 0x7FFFu + ((u >> 16) & 1u);
    return (unsigned short)(u >> 16);
}

// ---------------- CSR P1 + layer-0 linear + escore (merged) ----------------
__global__ void k_chist_lin0(const int* __restrict__ dst, int* __restrict__ bh,
                             const float* __restrict__ in,
                             const float* __restrict__ W,        // [4][64]
                             const float* __restrict__ asrc, const float* __restrict__ adst,
                             unsigned short* __restrict__ hcurb,
                             float* __restrict__ ssrc, float* __restrict__ sdst,
                             const float* __restrict__ eemb, float* __restrict__ escore) {
    int tid = threadIdx.x;
    if (blockIdx.x < NBLK) {
        __shared__ int lh[NBUCK];
        int blk = blockIdx.x;
        for (int i = tid; i < NBUCK; i += 256) lh[i] = 0;
        __syncthreads();
        int s = blk * EPB;
        for (int i = tid; i < EPB; i += 256) atomicAdd(&lh[dst[s + i] >> 9], 1);
        __syncthreads();
        for (int i = tid; i < NBUCK; i += 256) bh[i * NBLK + blk] = lh[i];
        return;
    }
    if (blockIdx.x >= NBLK + LIN0_BLOCKS) {
        if (tid < NLAYERS * ECLS * NHEADS) {
            int l = tid / (ECLS * NHEADS);
            int r = tid % (ECLS * NHEADS);
            int c = r >> 1;
            int h = r & 1;
            float s = 0.f;
            const float* ev = eemb + l * ECLS * HC + c * HC + h * 32;
            const float* av = asrc + l * HC + h * 32;   // att_src base passed
            for (int k = 0; k < 32; ++k) s += ev[k] * av[k];
            escore[tid] = s;
        }
        return;
    }
    int j = tid & 63;
    int wid = ((blockIdx.x - NBLK) * 256 + tid) >> 6;
    int nwaves = LIN0_BLOCKS * 4;

    float w0 = W[0 * HC + j], w1 = W[1 * HC + j], w2 = W[2 * HC + j], w3 = W[3 * HC + j];
    int head = j >> 5;
    int c = j & 31;
    float as = asrc[head * 32 + c];
    float ad = adst[head * 32 + c];

    for (int n = wid; n < N_NODES; n += nwaves) {
        int nu = __builtin_amdgcn_readfirstlane(n);
        float4 r = *(const float4*)(in + (size_t)nu * 4);
        float acc = r.x * w0 + r.y * w1 + r.z * w2 + r.w * w3;
        hcurb[(size_t)nu * HC + j] = f2bf(acc);
        float ps = acc * as;
        float pd = acc * ad;
        for (int off = 16; off > 0; off >>= 1) {
            ps += __shfl_down(ps, off, 32);
            pd += __shfl_down(pd, off, 32);
        }
        if (c == 0) {
            ssrc[nu * 2 + head] = ps;
            sdst[nu * 2 + head] = pd;
        }
    }
}

// P2a: per-bucket exclusive scan of the NBLK per-block counts.
__global__ void k_s1(const int* __restrict__ bh, int* __restrict__ bbase,
                     int* __restrict__ part) {
    __shared__ int tmp[NBLK];
    int tid = threadIdx.x;
    int i = blockIdx.x * NBLK + tid;
    int v = bh[i];
    tmp[tid] = v;
    __syncthreads();
    for (int off = 1; off < NBLK; off <<= 1) {
        int t = (tid >= off) ? tmp[tid - off] : 0;
        __syncthreads();
        tmp[tid] += t;
        __syncthreads();
    }
    bbase[i] = tmp[tid] - v;
    if (tid == NBLK - 1) part[blockIdx.x] = tmp[NBLK - 1];
}

// P3: coarse scatter, LDS-STAGED -> coalesced global writes.
__global__ void k_cscatter(const int* __restrict__ src, const int* __restrict__ dst,
                           const int* __restrict__ attr, const int* __restrict__ bbase,
                           const int* __restrict__ part, int* __restrict__ bkt) {
    __shared__ int tmp[256];
    __shared__ int cur[NBUCK];
    __shared__ int gadj[NBUCK];
    __shared__ int stage[EPB];            // 12.5 KB
    __shared__ unsigned char stb[EPB];    // 3.1 KB
    int tid = threadIdx.x, blk = blockIdx.x;
    int pv = (tid < NBUCK) ? part[tid] : 0;
    tmp[tid] = pv;
    __syncthreads();
    for (int off = 1; off < 256; off <<= 1) {
        int t = (tid >= off) ? tmp[tid - off] : 0;
        __syncthreads();
        tmp[tid] += t;
        __syncthreads();
    }
    if (tid < NBUCK) gadj[tid] = tmp[tid] - pv;
    if (tid < NBUCK) cur[tid] = 0;
    __syncthreads();
    int s0 = blk * EPB;
    for (int i = tid; i < EPB; i += 256) atomicAdd(&cur[dst[s0 + i] >> 9], 1);
    __syncthreads();
    int v = (tid < NBUCK) ? cur[tid] : 0;
    tmp[tid] = v;
    __syncthreads();
    for (int off = 1; off < 256; off <<= 1) {
        int t = (tid >= off) ? tmp[tid - off] : 0;
        __syncthreads();
        tmp[tid] += t;
        __syncthreads();
    }
    int ex = tmp[tid] - v;
    if (tid < NBUCK) {
        cur[tid] = ex;                                         // local cursor
        gadj[tid] += bbase[tid * NBLK + blk] - ex;             // global - local
    }
    __syncthreads();
    for (int i = tid; i < EPB; i += 256) {
        int e = s0 + i;
        int d = dst[e];
        int b = d >> 9;
        int pos = atomicAdd(&cur[b], 1);
        stage[pos] = src[e] | (attr[e] << 17) | ((d & 511) << 20);
        stb[pos] = (unsigned char)b;
    }
    __syncthreads();
    for (int i = tid; i < EPB; i += 256)
        bkt[gadj[stb[i]] + i] = stage[i];
}

// P4: fine sort within each bucket, LDS-STAGED (fallback if > FCAP).
__global__ void k_fine(const int* __restrict__ part, const int* __restrict__ bkt,
                       int* __restrict__ packed, int* __restrict__ rowstart) {
    __shared__ int hist[512];
    __shared__ int cur[512];
    __shared__ int pscan[512];
    __shared__ int stage[FCAP];           // 48 KB
    int b = blockIdx.x, tid = threadIdx.x;   // 512 threads
    int pv = (tid < NBUCK) ? part[tid] : 0;
    pscan[tid] = pv;
    __syncthreads();
    for (int off = 1; off < 512; off <<= 1) {
        int t = (tid >= off) ? pscan[tid - off] : 0;
        __syncthreads();
        pscan[tid] += t;
        __syncthreads();
    }
    int base = (b == 0) ? 0 : pscan[b - 1];
    int bend = pscan[b];
    int nb = bend - base;
    hist[tid] = 0;
    __syncthreads();
    for (int i = tid; i < nb; i += 512)
        atomicAdd(&hist[(bkt[base + i] >> 20) & 0x1FF], 1);
    __syncthreads();
    int v = hist[tid];
    for (int off = 1; off < 512; off <<= 1) {
        int t = (tid >= off) ? hist[tid - off] : 0;
        __syncthreads();
        hist[tid] += t;
        __syncthreads();
    }
    int excl = hist[tid] - v;
    int node = (b << 9) + tid;
    if (node <= N_NODES) rowstart[node] = base + excl;
    cur[tid] = excl;
    __syncthreads();
    if (nb <= FCAP) {
        for (int i = tid; i < nb; i += 512) {
            int p = bkt[base + i];
            int r = atomicAdd(&cur[(p >> 20) & 0x1FF], 1);
            stage[r] = p;
        }
        __syncthreads();
        for (int i = tid; i < nb; i += 512) packed[base + i] = stage[i];
    } else {
        for (int i = tid; i < nb; i += 512) {
            int p = bkt[base + i];
            int r = atomicAdd(&cur[(p >> 20) & 0x1FF], 1);
            packed[base + r] = p;
        }
    }
}

// ---------------- MFMA linear (layers 1..3) ----------------
__global__ void k_linmfma(const unsigned short* __restrict__ actB,
                          const float* __restrict__ Wl,       // [64][64] fp32
                          const float* __restrict__ asrc,     // [64]
                          const float* __restrict__ adst,     // [64]
                          unsigned short* __restrict__ hcurb,
                          float* __restrict__ ssrc, float* __restrict__ sdst) {
    __shared__ uint4 WB[512];
    __shared__ unsigned short Cb[4][1024];
    int tid = threadIdx.x;
    int lane = tid & 63;
    int w = tid >> 6;
    int q = lane >> 4;
    int c = lane & 15;

    for (int rid = tid; rid < 512; rid += 256) {
        int kk = rid >> 8;
        int t  = (rid >> 6) & 3;
        int ln = rid & 63;
        int qq = ln >> 4, cc = ln & 15;
        unsigned int u[4];
        #pragma unroll
        for (int jj = 0; jj < 4; ++jj) {
            float v0 = Wl[(kk * 32 + qq * 8 + jj * 2 + 0) * 64 + 16 * t + cc];
            float v1 = Wl[(kk * 32 + qq * 8 + jj * 2 + 1) * 64 + 16 * t + cc];
            u[jj] = (unsigned int)f2bf(v0) | ((unsigned int)f2bf(v1) << 16);
        }
        WB[rid] = make_uint4(u[0], u[1], u[2], u[3]);
    }
    __syncthreads();

    short8 bfr[2][4];
    #pragma unroll
    for (int kk = 0; kk < 2; ++kk)
        #pragma unroll
        for (int t = 0; t < 4; ++t) {
            F8 tmp; tmp.u = WB[(kk * 4 + t) * 64 + lane];
            bfr[kk][t] = tmp.s;
        }

    float as_[4], ad_[4];
    #pragma unroll
    for (int t = 0; t < 4; ++t) {
        as_[t] = asrc[16 * t + c];
        ad_[t] = adst[16 * t + c];
    }

    int wid = (blockIdx.x * 256 + tid) >> 6;
    int nwaves = gridDim.x * 4;

    for (int g = wid; g < NGRP; g += nwaves) {
        int base = g * 16;
        F8 a0, a1;
        a0.u = *(const uint4*)(actB + (size_t)(base + c) * HC + q * 8);
        a1.u = *(const uint4*)(actB + (size_t)(base + c) * HC + 32 + q * 8);

        floatx4 acc[4];
        #pragma unroll
        for (int t = 0; t < 4; ++t) {
            acc[t] = (floatx4){0.f, 0.f, 0.f, 0.f};
            acc[t] = __builtin_amdgcn_mfma_f32_16x16x32_bf16(a0.s, bfr[0][t], acc[t], 0, 0, 0);
            acc[t] = __builtin_amdgcn_mfma_f32_16x16x32_bf16(a1.s, bfr[1][t], acc[t], 0, 0, 0);
        }

        #pragma unroll
        for (int r = 0; r < 4; ++r) {
            float h0s = acc[0][r] * as_[0] + acc[1][r] * as_[1];
            float h1s = acc[2][r] * as_[2] + acc[3][r] * as_[3];
            float h0d = acc[0][r] * ad_[0] + acc[1][r] * ad_[1];
            float h1d = acc[2][r] * ad_[2] + acc[3][r] * ad_[3];
            #pragma unroll
            for (int off = 1; off < 16; off <<= 1) {
                h0s += __shfl_xor(h0s, off, 64);
                h1s += __shfl_xor(h1s, off, 64);
                h0d += __shfl_xor(h0d, off, 64);
                h1d += __shfl_xor(h1d, off, 64);
            }
            if (c == 0) {
                int node = base + q * 4 + r;
                *(float2*)(ssrc + node * 2) = make_float2(h0s, h1s);
                *(float2*)(sdst + node * 2) = make_float2(h0d, h1d);
            }
        }

        #pragma unroll
        for (int t = 0; t < 4; ++t)
            #pragma unroll
            for (int r = 0; r < 4; ++r)
                Cb[w][(q * 4 + r) * 64 + 16 * t + c] = f2bf(acc[t][r]);
        __builtin_amdgcn_wave_barrier();
        const uint4* cf = (const uint4*)&Cb[w][0];
        uint4* gout = (uint4*)(hcurb + (size_t)base * HC);
        gout[lane] = cf[lane];
        gout[64 + lane] = cf[64 + lane];
        __builtin_amdgcn_wave_barrier();
    }
}

// ---------------- fused edge pipeline ----------------
// One wave per dst node. Inner loop uses PACKED fp32 (float2 ext-vector ->
// v_pk_add_f32 / v_pk_fma_f32): core 24 -> 16 VALU ops/edge. Slot reduction
// via LDS transpose (4 ds_write_b64 + 8 ds_read_b32; bank-floor). The 1.6M
// SQ_LDS_BANK_CONFLICT is the wave64 b128/b64 multi-cycle floor, not real
// conflicts (measured: stride-64 vs -68 identical).
template <int NW, bool LAST>
__global__ void k_edge(const int* __restrict__ rowstart, const int* __restrict__ packed,
                       const float* __restrict__ ssrc, const float* __restrict__ sdst,
                       const float* __restrict__ escore_l,   // [5][2]
                       const unsigned short* __restrict__ hcurb, // [N][64] bf16
                       const float* __restrict__ eemb_l,     // [5][64]
                       const float* __restrict__ bias_l,     // [64]
                       unsigned short* __restrict__ actnext, float* __restrict__ out) {
    __shared__ float chbuf[NW][8 * CHS];  // [slot][channel] partials
    __shared__ float obuf[2][64];
    int w = threadIdx.x >> 6;
    int n = LAST ? (blockIdx.x * 4 + w) : (blockIdx.x * NW + w);
    int lane = threadIdx.x & 63;
    int sub = lane >> 3;
    int q   = lane & 7;
    int h   = q >> 2;

    int beg = rowstart[n];
    int end = rowstart[n + 1];
    float sd = sdst[n * 2 + h];

    v2f acc0 = {0.f, 0.f}, acc1 = {0.f, 0.f}, acc2 = {0.f, 0.f}, acc3 = {0.f, 0.f};
    float ssum = 0.f;
    for (int i = beg + sub; i < end; i += 8) {
        int p = packed[i];
        int s = p & 0x1FFFF;
        int a = (p >> 17) & 7;
        float lg = sd + ssrc[s * 2 + h] + escore_l[a * 2 + h];
        lg = lg >= 0.f ? lg : 0.2f * lg;
        float wt = __expf(lg);
        uint4 hv = *(const uint4*)(hcurb + (size_t)s * HC + q * 8);
        const v2f* ep = (const v2f*)(eemb_l + a * HC + q * 8);
        v2f wt2 = {wt, wt};
        v2f m0 = {bf_lo(hv.x), bf_hi(hv.x)};
        v2f m1 = {bf_lo(hv.y), bf_hi(hv.y)};
        v2f m2 = {bf_lo(hv.z), bf_hi(hv.z)};
        v2f m3 = {bf_lo(hv.w), bf_hi(hv.w)};
        acc0 += wt2 * (m0 + ep[0]);      // v_pk_add_f32 + v_pk_fma_f32
        acc1 += wt2 * (m1 + ep[1]);
        acc2 += wt2 * (m2 + ep[2]);
        acc3 += wt2 * (m3 + ep[3]);
        ssum += wt;
    }
    // slot partials -> LDS (4 x b64, bank-floor)
    v2f* cb = (v2f*)&chbuf[w][sub * CHS + q * 8];
    cb[0] = acc0;
    cb[1] = acc1;
    cb[2] = acc2;
    cb[3] = acc3;
    // ssum: 3-round butterfly, then pick head of CHANNEL `lane` (= lane>>5)
    for (int off = 8; off < 64; off <<= 1) ssum += __shfl_xor(ssum, off, 64);
    float ssum_h = __shfl(ssum, (lane >> 5) * 4, 64);
    float inv = 1.f / (ssum_h + 1e-16f);
    __builtin_amdgcn_wave_barrier();            // DS ops in-order per wave
    float s = 0.f;
    #pragma unroll
    for (int k = 0; k < 8; ++k) s += chbuf[w][k * CHS + lane];
    float v = s * inv + bias_l[lane];
    float o = v > 0.f ? v : (__expf(v) - 1.f);
    if (!LAST) {
        actnext[(size_t)n * HC + lane] = f2bf(o);
    } else {
        obuf[w][lane] = o;                      // w=0: user 4b, w=1: item 4b+1
        __syncthreads();
        if (w == 0) {
            float p = obuf[0][lane] * obuf[1][lane];
            for (int off = 32; off > 0; off >>= 1) p += __shfl_down(p, off, 64);
            if (lane == 0) out[blockIdx.x] = p;
        }
    }
}

// ---------------- launch ----------------
extern "C" void kernel_launch(void* const* d_in, const int* in_sizes, int n_in,
                              void* d_out, int out_size, void* d_ws, size_t ws_size,
                              hipStream_t stream) {
    const float* x       = (const float*)d_in[0];   // [N,4]
    const float* W0      = (const float*)d_in[1];   // [4,64]
    const float* W13     = (const float*)d_in[2];   // [3,64,64]
    const float* eemb    = (const float*)d_in[3];   // [4,5,64]
    const float* att_src = (const float*)d_in[4];   // [4,2,32]
    const float* att_dst = (const float*)d_in[5];   // [4,2,32]
    const float* bias    = (const float*)d_in[6];   // [4,64]
    const int*   eidx    = (const int*)d_in[7];     // [2,E]
    const int*   eattr   = (const int*)d_in[8];     // [E]
    float* out = (float*)d_out;

    const int* src = eidx;
    const int* dst = eidx + N_EDGES;

    char* wsb = (char*)d_ws;
    size_t off = 0;
    auto alloc = [&](size_t bytes) { char* p = wsb + off; off += (bytes + 255) & ~(size_t)255; return p; };
    unsigned short* hcurb  = (unsigned short*)alloc((size_t)N_NODES * HC * 2);
    unsigned short* actB   = (unsigned short*)alloc((size_t)N_NODES * HC * 2);
    float*          ssrc   = (float*)alloc((size_t)N_NODES * 2 * 4);
    float*          sdst   = (float*)alloc((size_t)N_NODES * 2 * 4);
    float*          escore = (float*)alloc(NLAYERS * ECLS * NHEADS * 4);
    int*            bh     = (int*)alloc((size_t)NBUCK * NBLK * 4);
    int*            bbase  = (int*)alloc((size_t)NBUCK * NBLK * 4);
    int*            part   = (int*)alloc(256 * 4);
    int*            rowstart = (int*)alloc(((size_t)N_NODES + 1) * 4);
    int*            bkt    = (int*)alloc((size_t)N_EDGES * 4);
    int*            packed = (int*)alloc((size_t)N_EDGES * 4);

    // ---- CSR build P1 + layer-0 linear + escore (merged) ----
    k_chist_lin0<<<NBLK + LIN0_BLOCKS + 1, 256, 0, stream>>>(
        dst, bh, x, W0, att_src, att_dst, hcurb, ssrc, sdst, eemb, escore);
    k_s1<<<NBUCK, NBLK, 0, stream>>>(bh, bbase, part);
    k_cscatter<<<NBLK, 256, 0, stream>>>(src, dst, eattr, bbase, part, bkt);
    k_fine<<<NBUCK, 512, 0, stream>>>(part, bkt, packed, rowstart);

    for (int l = 0; l < NLAYERS; ++l) {
        if (l > 0) {
            k_linmfma<<<512, 256, 0, stream>>>(
                actB, W13 + (size_t)(l - 1) * HC * HC,
                att_src + l * HC, att_dst + l * HC, hcurb, ssrc, sdst);
        }
        const float* esl = escore + l * ECLS * NHEADS;
        const float* el  = eemb + (size_t)l * ECLS * HC;
        const float* bl  = bias + l * HC;
        if (l < NLAYERS - 1)
            k_edge<1, false><<<N_NODES, 64, 0, stream>>>(
                rowstart, packed, ssrc, sdst, esl, hcurb, el, bl, actB, nullptr);
        else
            k_edge<2, true><<<N_NODES / 4, 128, 0, stream>>>(
                rowstart, packed, ssrc, sdst, esl, hcurb, el, bl, nullptr, out);
    }
}